// Round 10
// baseline (59586.414 us; speedup 1.0000x reference)
//
#include <hip/hip_runtime.h>
#include <math.h>

#define BB 256   // batch
#define TT 512   // encoder seq len
#define DD 64    // state dim
#define HH 512   // hidden dim
#define FF 32    // fc_seq_len (decoder steps)
#define HSTR 196 // hbuf row stride (floats); 16B-aligned rows

__device__ __forceinline__ float sigmoidf_(float x) { return 1.0f / (1.0f + __expf(-x)); }

// ---------------- K-split GRU step, weights in registers ----------------
// grid (64, 4): j-tile = blockIdx.x (8 cols), batch group = blockIdx.y (64 rows).
// 256 thr: ks = tid&15 (16 K-slices of 36 over K=576=[x:64|h:512]),
//          jq = tid>>4: jj = jq&7 (j-col), bh = jq>>3 (32-row half).
// Per thread: 120 weight VGPRs (loaded from L2 each step), 4x32 accumulators;
// h staged in LDS in 3 phases of 192 cols, read b128 (16 addrs x 4-way bcast =
// ~2-clk floor, conflict-free). Butterfly reduce over ks (in-wave, masks 1..8).
// Gate n keeps x-part (i_n) and h-part (h_n) separate: phase-0 n-weights are
// zero-split into wnx (cols<64) / wnh (cols>=64) so acc indexing stays static.

// stage phase p: 64 rows x 48 float4 = cols [p*192, p*192+192) of [x|h]
__device__ __forceinline__ void stage_issue_ks(float4* pre, const float* __restrict__ x,
                                               int xs, const float* __restrict__ h,
                                               int p, int b0, int tid) {
    #pragma unroll
    for (int u = 0; u < 12; ++u) {
        const int i = u * 256 + tid;
        const int r = i / 48, c4 = i - r * 48;
        const int col4 = p * 48 + c4;
        float4 v = make_float4(0.f, 0.f, 0.f, 0.f);
        if (col4 < 16)      v = *(const float4*)&x[(b0 + r) * xs + col4 * 4];
        else if (h != nullptr) v = *(const float4*)&h[(b0 + r) * HH + (col4 - 16) * 4];
        pre[u] = v;
    }
}
__device__ __forceinline__ void stage_commit_ks(float (*hbuf)[HSTR], const float4* pre, int tid) {
    #pragma unroll
    for (int u = 0; u < 12; ++u) {
        const int i = u * 256 + tid;
        const int r = i / 48, c4 = i - r * 48;
        *(float4*)&hbuf[r][c4 * 4] = pre[u];
    }
}

template <bool XSPLIT>
__device__ __forceinline__ void compute_ph(const float (*hbuf)[HSTR], int ks, int bh,
                                           const float* wr, const float* wz,
                                           const float* wnh, const float* wnx,
                                           float* ar, float* az, float* ain, float* ahn) {
    #pragma unroll
    for (int b = 0; b < 32; ++b) {
        const float* row = &hbuf[bh * 32 + b][ks * 12];
        const float4 h0 = *(const float4*)&row[0];
        const float4 h1 = *(const float4*)&row[4];
        const float4 h2 = *(const float4*)&row[8];
        const float hv[12] = {h0.x, h0.y, h0.z, h0.w, h1.x, h1.y, h1.z, h1.w,
                              h2.x, h2.y, h2.z, h2.w};
        #pragma unroll
        for (int c = 0; c < 12; ++c) {
            ar[b] = fmaf(hv[c], wr[c], ar[b]);
            az[b] = fmaf(hv[c], wz[c], az[b]);
            if (XSPLIT) {
                ain[b] = fmaf(hv[c], wnx[c], ain[b]);
                ahn[b] = fmaf(hv[c], wnh[c], ahn[b]);
            } else {
                ahn[b] = fmaf(hv[c], wnh[c], ahn[b]);
            }
        }
    }
}

__global__ void __launch_bounds__(256, 1) gru_step_ks(
    const float* __restrict__ x, int xs,            // [BB, *] rows at stride xs
    const float* __restrict__ h,                    // [BB, HH] or nullptr (zeros)
    const float* __restrict__ W_ih, const float* __restrict__ W_hh,
    const float* __restrict__ b_ih, const float* __restrict__ b_hh,
    float* __restrict__ hnew,                       // [BB, HH]
    float* __restrict__ h2, int h2s)                // optional extra write (h_seq)
{
    __shared__ float hbuf[64][HSTR];                // 50176 B
    const int tid = threadIdx.x;
    const int j0 = blockIdx.x * 8, b0 = blockIdx.y * 64;
    const int ks = tid & 15, jq = tid >> 4;
    const int jj = jq & 7, bh = jq >> 3;
    const int j = j0 + jj;

    // ---- weights -> registers (cols [x:0..63 | h:64..575], 12 per phase) ----
    float wr[3][12], wz[3][12], wnh[3][12], wnx[12];
    #pragma unroll
    for (int p = 0; p < 3; ++p) {
        const int base = p * 192 + ks * 12;
        #pragma unroll
        for (int g = 0; g < 3; ++g) {
            float tw[12];
            const int rowi = g * HH + j;
            if (base >= DD) {                       // pure W_hh, 16B-aligned
                const float* src = &W_hh[rowi * HH + base - DD];
                #pragma unroll
                for (int q = 0; q < 3; ++q) {
                    const float4 v = *(const float4*)&src[q * 4];
                    tw[q*4] = v.x; tw[q*4+1] = v.y; tw[q*4+2] = v.z; tw[q*4+3] = v.w;
                }
            } else if (base + 12 <= DD) {           // pure W_ih, 16B-aligned
                const float* src = &W_ih[rowi * DD + base];
                #pragma unroll
                for (int q = 0; q < 3; ++q) {
                    const float4 v = *(const float4*)&src[q * 4];
                    tw[q*4] = v.x; tw[q*4+1] = v.y; tw[q*4+2] = v.z; tw[q*4+3] = v.w;
                }
            } else {                                // straddles x/h (ks==5, p==0)
                #pragma unroll
                for (int c = 0; c < 12; ++c) {
                    const int col = base + c;
                    tw[c] = (col < DD) ? W_ih[rowi * DD + col]
                                       : W_hh[rowi * HH + col - DD];
                }
            }
            #pragma unroll
            for (int c = 0; c < 12; ++c) {
                if (g == 0)      wr[p][c]  = tw[c];
                else if (g == 1) wz[p][c]  = tw[c];
                else             wnh[p][c] = tw[c];
            }
        }
    }
    // split n-gate phase-0 weights into x-part / h-part (zero-masked)
    #pragma unroll
    for (int c = 0; c < 12; ++c) {
        const int col = ks * 12 + c;
        const float wn = wnh[0][c];
        wnx[c]    = (col < DD) ? wn : 0.f;
        wnh[0][c] = (col < DD) ? 0.f : wn;
    }

    float ar[32], az[32], ain[32], ahn[32];
    #pragma unroll
    for (int b = 0; b < 32; ++b) { ar[b] = az[b] = ain[b] = ahn[b] = 0.f; }

    float4 pre[12];
    // ---- phase 0 (x cols 0..63 + h cols 0..127) ----
    stage_issue_ks(pre, x, xs, h, 0, b0, tid);
    stage_commit_ks(hbuf, pre, tid);
    __syncthreads();
    if (h) stage_issue_ks(pre, x, xs, h, 1, b0, tid);
    compute_ph<true>(hbuf, ks, bh, wr[0], wz[0], wnh[0], wnx, ar, az, ain, ahn);
    __syncthreads();
    if (h) {
        // ---- phase 1 (h cols 128..319) ----
        stage_commit_ks(hbuf, pre, tid);
        __syncthreads();
        stage_issue_ks(pre, x, xs, h, 2, b0, tid);
        compute_ph<false>(hbuf, ks, bh, wr[1], wz[1], wnh[1], wnx, ar, az, ain, ahn);
        __syncthreads();
        // ---- phase 2 (h cols 320..511) ----
        stage_commit_ks(hbuf, pre, tid);
        __syncthreads();
        compute_ph<false>(hbuf, ks, bh, wr[2], wz[2], wnh[2], wnx, ar, az, ain, ahn);
    }

    // ---- butterfly reduce over the 16 ks-lanes (in-wave: masks 1,2,4,8) ----
    #pragma unroll
    for (int b = 0; b < 32; ++b) {
        float vr = ar[b], vz = az[b], vi = ain[b], vh = ahn[b];
        #pragma unroll
        for (int m = 1; m < 16; m <<= 1) {
            vr += __shfl_xor(vr, m, 64);
            vz += __shfl_xor(vz, m, 64);
            vi += __shfl_xor(vi, m, 64);
            vh += __shfl_xor(vh, m, 64);
        }
        ar[b] = vr; az[b] = vz; ain[b] = vi; ahn[b] = vh;
    }

    // ---- epilogue: lane ks owns rows 2ks, 2ks+1 of its 32-row half ----
    const float br  = b_ih[j] + b_hh[j];
    const float bz  = b_ih[HH + j] + b_hh[HH + j];
    const float bin = b_ih[2 * HH + j];
    const float bhn = b_hh[2 * HH + j];
    #pragma unroll
    for (int b = 0; b < 32; ++b) {
        if ((b >> 1) == ks) {
            const int bg = b0 + bh * 32 + b;
            const float r = sigmoidf_(ar[b] + br);
            const float z = sigmoidf_(az[b] + bz);
            const float hold = h ? h[bg * HH + j] : 0.f;
            const float n = tanhf(ain[b] + bin + r * (ahn[b] + bhn));
            const float hn = (1.f - z) * n + z * hold;
            hnew[bg * HH + j] = hn;
            if (h2) h2[bg * h2s + j] = hn;
        }
    }
}

// ---------------- fc kernels (round-3/9-verified) ----------------
struct SmemOld { float hs[16][34]; float ws[96][34]; };

__global__ __launch_bounds__(256) void fc1_relu(
    const float* __restrict__ h, const float* __restrict__ wsrc,
    const float* __restrict__ bias, float* __restrict__ out) {
    __shared__ SmemOld sm;
    float (*hs)[34] = sm.hs; float (*ws)[34] = sm.ws;
    const int tid = threadIdx.x;
    const int jj = tid & 31, bb = tid >> 5;
    const int j0 = blockIdx.x * 32, b0 = blockIdx.y * 16;
    float a0 = 0.f, a1 = 0.f;
    for (int kt = 0; kt < HH; kt += 32) {
        { const int r = tid >> 4, c2 = (tid & 15) * 2;
          *(float2*)&hs[r][c2] = *(const float2*)&h[(b0 + r) * HH + kt + c2]; }
        #pragma unroll
        for (int i = 0; i < 2; ++i) {
            const int idx = i * 256 + tid, r = idx >> 4, c2 = (idx & 15) * 2;
            *(float2*)&ws[r][c2] = *(const float2*)&wsrc[(j0 + r) * HH + kt + c2];
        }
        __syncthreads();
        #pragma unroll
        for (int k = 0; k < 32; k += 2) {
            const float2 h0 = *(const float2*)&hs[bb][k];
            const float2 h1 = *(const float2*)&hs[bb + 8][k];
            const float2 w0 = *(const float2*)&ws[jj][k];
            a0 = fmaf(h0.x, w0.x, a0); a0 = fmaf(h0.y, w0.y, a0);
            a1 = fmaf(h1.x, w0.x, a1); a1 = fmaf(h1.y, w0.y, a1);
        }
        __syncthreads();
    }
    const float b = bias[j0 + jj];
    out[(b0 + bb) * HH + j0 + jj]     = fmaxf(a0 + b, 0.f);
    out[(b0 + bb + 8) * HH + j0 + jj] = fmaxf(a1 + b, 0.f);
}

__global__ __launch_bounds__(256) void fc2_out(
    const float* __restrict__ a, const float* __restrict__ wsrc,
    const float* __restrict__ bias, float* __restrict__ s_buf,
    float* __restrict__ s_out, int s_stride) {
    __shared__ SmemOld sm;
    float (*as)[34] = sm.hs; float (*ws)[34] = sm.ws;
    const int tid = threadIdx.x;
    const int d = tid & 63, bb = tid >> 6;
    const int b0 = blockIdx.x * 4;
    float acc = 0.f;
    for (int kt = 0; kt < HH; kt += 32) {
        if (tid < 64) { const int r = tid >> 4, c2 = (tid & 15) * 2;
            *(float2*)&as[r][c2] = *(const float2*)&a[(b0 + r) * HH + kt + c2]; }
        #pragma unroll
        for (int i = 0; i < 4; ++i) {
            const int idx = i * 256 + tid, r = idx >> 4, c2 = (idx & 15) * 2;
            *(float2*)&ws[r][c2] = *(const float2*)&wsrc[r * HH + kt + c2];
        }
        __syncthreads();
        #pragma unroll
        for (int k = 0; k < 32; k += 2) {
            const float2 av = *(const float2*)&as[bb][k];
            const float2 wv = *(const float2*)&ws[d][k];
            acc = fmaf(av.x, wv.x, acc); acc = fmaf(av.y, wv.y, acc);
        }
        __syncthreads();
    }
    const float v = acc + bias[d];
    s_buf[(b0 + bb) * DD + d] = v;
    s_out[(b0 + bb) * s_stride + d] = v;
}

extern "C" void kernel_launch(void* const* d_in, const int* in_sizes, int n_in,
                              void* d_out, int out_size, void* d_ws, size_t ws_size,
                              hipStream_t stream) {
    const float* state_seq = (const float*)d_in[0];  // [256,512,64]
    const float* W_ih  = (const float*)d_in[1];      // [1536,64]
    const float* W_hh  = (const float*)d_in[2];      // [1536,512]
    const float* b_ih  = (const float*)d_in[3];
    const float* b_hh  = (const float*)d_in[4];
    const float* fc1_w = (const float*)d_in[5];      // [512,512]
    const float* fc1_b = (const float*)d_in[6];
    const float* fc2_w = (const float*)d_in[7];      // [64,512]
    const float* fc2_b = (const float*)d_in[8];

    float* out_s = (float*)d_out;                    // [256, 32, 64]
    float* out_h = out_s + BB * FF * DD;             // [256, 32, 512]

    float* hA   = (float*)d_ws;
    float* hB   = hA + BB * HH;
    float* aBuf = hB + BB * HH;
    float* sBuf = aBuf + BB * HH;

    const dim3 blk(256);
    const dim3 gruGrid(HH / 8, BB / 64);             // (64, 4)

    // ---- encoder: 512 per-step launches (launch boundary = h sync) ----
    const float* hcur = nullptr;
    for (int t = 0; t < TT; ++t) {
        float* hout = (t & 1) ? hB : hA;
        float* hout2 = (t == TT - 1) ? out_h : nullptr;   // h_seq[:,0,:]
        gru_step_ks<<<gruGrid, blk, 0, stream>>>(state_seq + t * DD, TT * DD, hcur,
                                                 W_ih, W_hh, b_ih, b_hh,
                                                 hout, hout2, FF * HH);
        hcur = hout;
    }

    // ---- decoder: 32 fc_predicts, 31 GRU steps ----
    for (int t = 0; t < FF; ++t) {
        fc1_relu<<<dim3(HH / 32, BB / 16), blk, 0, stream>>>(hcur, fc1_w, fc1_b, aBuf);
        fc2_out<<<dim3(BB / 4), blk, 0, stream>>>(aBuf, fc2_w, fc2_b, sBuf,
                                                  out_s + t * DD, FF * DD);
        if (t < FF - 1) {
            float* hout = (hcur == hA) ? hB : hA;
            gru_step_ks<<<gruGrid, blk, 0, stream>>>(sBuf, DD, hcur,
                                                     W_ih, W_hh, b_ih, b_hh,
                                                     hout, out_h + (t + 1) * HH, FF * HH);
            hcur = hout;
        }
    }
}

// Round 11
// 17738.530 us; speedup vs baseline: 3.3592x; 3.3592x over previous
//
#include <hip/hip_runtime.h>
#include <math.h>

#define BB 256   // batch
#define TT 512   // encoder seq len
#define DD 64    // state dim
#define HH 512   // hidden dim
#define FF 32    // fc_seq_len (decoder steps)

__device__ __forceinline__ float sigmoidf_(float x) { return 1.0f / (1.0f + __expf(-x)); }

// ---------------- wave-per-j GRU step ----------------
// grid (HH/4=128, BB/64=4), block 256 (4 waves). Wave wv owns j = bx*4+wv,
// lane l owns batch row b0+l. Full K accumulated in-lane (no reduce).
// K = [x:64 | h:512] in 9 chunks of 64 cols. LDS: double-buffered 64x16
// float4 tile, XOR-swizzled (quad c4 stored at c4^(r&15)) -> both the
// ds_write_b128 staging and the per-lane ds_read_b128 are conflict-free.
// Weights are read through wave-uniform addresses (readfirstlane j) ->
// scalar loads; FMA = VGPR(h) x SGPR(w).

__device__ __forceinline__ void stage_issue_wj(float4* v, const float* __restrict__ src,
                                               int rs, int col0, int b0, int tid) {
    #pragma unroll
    for (int u = 0; u < 4; ++u) {
        const int idx = u * 256 + tid, r = idx >> 4, c4 = idx & 15;
        v[u] = *(const float4*)&src[(b0 + r) * rs + col0 + c4 * 4];
    }
}
__device__ __forceinline__ void stage_commit_wj(float4 (*buf)[16], const float4* v, int tid) {
    #pragma unroll
    for (int u = 0; u < 4; ++u) {
        const int idx = u * 256 + tid, r = idx >> 4, c4 = idx & 15;
        buf[r][c4 ^ (r & 15)] = v[u];
    }
}

// one 64-col chunk: 4 blocks of 16 K. wrow/wzrow/wnrow = row base pointers
// (wave-uniform), kb0 = starting col within those rows.
__device__ __forceinline__ void compute_chunk_wj(
    const float4 (*buf)[16], int lane,
    const float* __restrict__ wr_row, const float* __restrict__ wz_row,
    const float* __restrict__ wn_row, int kb0,
    float& ar, float& az, float& an) {
    #pragma unroll
    for (int blk = 0; blk < 4; ++blk) {
        float4 hq[4];
        #pragma unroll
        for (int q = 0; q < 4; ++q)
            hq[q] = buf[lane][(blk * 4 + q) ^ (lane & 15)];
        const float4* wr4 = (const float4*)&wr_row[kb0 + blk * 16];
        const float4* wz4 = (const float4*)&wz_row[kb0 + blk * 16];
        const float4* wn4 = (const float4*)&wn_row[kb0 + blk * 16];
        #pragma unroll
        for (int q = 0; q < 4; ++q) {
            const float4 w0 = wr4[q], w1 = wz4[q], w2 = wn4[q];
            ar = fmaf(hq[q].x, w0.x, ar); ar = fmaf(hq[q].y, w0.y, ar);
            ar = fmaf(hq[q].z, w0.z, ar); ar = fmaf(hq[q].w, w0.w, ar);
            az = fmaf(hq[q].x, w1.x, az); az = fmaf(hq[q].y, w1.y, az);
            az = fmaf(hq[q].z, w1.z, az); az = fmaf(hq[q].w, w1.w, az);
            an = fmaf(hq[q].x, w2.x, an); an = fmaf(hq[q].y, w2.y, an);
            an = fmaf(hq[q].z, w2.z, an); an = fmaf(hq[q].w, w2.w, an);
        }
    }
}

__global__ void __launch_bounds__(256, 2) gru_step_wj(
    const float* __restrict__ x, int xs,            // [BB,*] rows at stride xs
    const float* __restrict__ h,                    // [BB,HH] or nullptr (zeros)
    const float* __restrict__ W_ih, const float* __restrict__ W_hh,
    const float* __restrict__ b_ih, const float* __restrict__ b_hh,
    float* __restrict__ hnew,                       // [BB,HH]
    float* __restrict__ h2, int h2s)                // optional extra write
{
    __shared__ float4 buf[2][64][16];               // 32 KiB
    const int tid = threadIdx.x;
    const int lane = tid & 63, wv = tid >> 6;
    const int b0 = blockIdx.y * 64;
    const int j = __builtin_amdgcn_readfirstlane(blockIdx.x * 4 + wv);

    // wave-uniform weight row bases
    const float* wr_ih = &W_ih[(0 * HH + j) * DD];
    const float* wz_ih = &W_ih[(1 * HH + j) * DD];
    const float* wn_ih = &W_ih[(2 * HH + j) * DD];
    const float* wr_hh = &W_hh[(0 * HH + j) * HH];
    const float* wz_hh = &W_hh[(1 * HH + j) * HH];
    const float* wn_hh = &W_hh[(2 * HH + j) * HH];

    float ar = 0.f, az = 0.f, ain = 0.f, ahn = 0.f;
    float4 v[4];

    // stage chunk 0 (x cols 0..63) into buf[0]
    stage_issue_wj(v, x, xs, 0, b0, tid);
    stage_commit_wj(buf[0], v, tid);
    __syncthreads();

    // chunk 0: x part (W_ih), n-gate -> ain
    if (h) stage_issue_wj(v, h, HH, 0, b0, tid);    // chunk 1 = h cols 0..63
    compute_chunk_wj(buf[0], lane, wr_ih, wz_ih, wn_ih, 0, ar, az, ain);
    if (h) stage_commit_wj(buf[1], v, tid);
    __syncthreads();

    // chunks 1..8: h part (W_hh), n-gate -> ahn
    if (h) {
        for (int c = 1; c < 9; ++c) {
            if (c < 8) stage_issue_wj(v, h, HH, c * 64, b0, tid);
            compute_chunk_wj(buf[c & 1], lane, wr_hh, wz_hh, wn_hh,
                             (c - 1) * 64, ar, az, ahn);
            if (c < 8) stage_commit_wj(buf[(c + 1) & 1], v, tid);
            __syncthreads();
        }
    }

    // epilogue: n = tanh(i_n + r*h_n); h' = (1-z)n + z h
    const float br  = b_ih[j] + b_hh[j];
    const float bz  = b_ih[HH + j] + b_hh[HH + j];
    const float bin = b_ih[2 * HH + j];
    const float bhn = b_hh[2 * HH + j];
    const int bg = b0 + lane;
    const float r = sigmoidf_(ar + br);
    const float z = sigmoidf_(az + bz);
    const float hold = h ? h[bg * HH + j] : 0.f;
    const float n = tanhf(ain + bin + r * (ahn + bhn));
    const float hn = (1.f - z) * n + z * hold;
    hnew[bg * HH + j] = hn;
    if (h2) h2[bg * h2s + j] = hn;
}

// ---------------- fc kernels (round-3/9-verified) ----------------
struct SmemOld { float hs[16][34]; float ws[96][34]; };

__global__ __launch_bounds__(256) void fc1_relu(
    const float* __restrict__ h, const float* __restrict__ wsrc,
    const float* __restrict__ bias, float* __restrict__ out) {
    __shared__ SmemOld sm;
    float (*hs)[34] = sm.hs; float (*ws)[34] = sm.ws;
    const int tid = threadIdx.x;
    const int jj = tid & 31, bb = tid >> 5;
    const int j0 = blockIdx.x * 32, b0 = blockIdx.y * 16;
    float a0 = 0.f, a1 = 0.f;
    for (int kt = 0; kt < HH; kt += 32) {
        { const int r = tid >> 4, c2 = (tid & 15) * 2;
          *(float2*)&hs[r][c2] = *(const float2*)&h[(b0 + r) * HH + kt + c2]; }
        #pragma unroll
        for (int i = 0; i < 2; ++i) {
            const int idx = i * 256 + tid, r = idx >> 4, c2 = (idx & 15) * 2;
            *(float2*)&ws[r][c2] = *(const float2*)&wsrc[(j0 + r) * HH + kt + c2];
        }
        __syncthreads();
        #pragma unroll
        for (int k = 0; k < 32; k += 2) {
            const float2 h0 = *(const float2*)&hs[bb][k];
            const float2 h1 = *(const float2*)&hs[bb + 8][k];
            const float2 w0 = *(const float2*)&ws[jj][k];
            a0 = fmaf(h0.x, w0.x, a0); a0 = fmaf(h0.y, w0.y, a0);
            a1 = fmaf(h1.x, w0.x, a1); a1 = fmaf(h1.y, w0.y, a1);
        }
        __syncthreads();
    }
    const float b = bias[j0 + jj];
    out[(b0 + bb) * HH + j0 + jj]     = fmaxf(a0 + b, 0.f);
    out[(b0 + bb + 8) * HH + j0 + jj] = fmaxf(a1 + b, 0.f);
}

__global__ __launch_bounds__(256) void fc2_out(
    const float* __restrict__ a, const float* __restrict__ wsrc,
    const float* __restrict__ bias, float* __restrict__ s_buf,
    float* __restrict__ s_out, int s_stride) {
    __shared__ SmemOld sm;
    float (*as)[34] = sm.hs; float (*ws)[34] = sm.ws;
    const int tid = threadIdx.x;
    const int d = tid & 63, bb = tid >> 6;
    const int b0 = blockIdx.x * 4;
    float acc = 0.f;
    for (int kt = 0; kt < HH; kt += 32) {
        if (tid < 64) { const int r = tid >> 4, c2 = (tid & 15) * 2;
            *(float2*)&as[r][c2] = *(const float2*)&a[(b0 + r) * HH + kt + c2]; }
        #pragma unroll
        for (int i = 0; i < 4; ++i) {
            const int idx = i * 256 + tid, r = idx >> 4, c2 = (idx & 15) * 2;
            *(float2*)&ws[r][c2] = *(const float2*)&wsrc[r * HH + kt + c2];
        }
        __syncthreads();
        #pragma unroll
        for (int k = 0; k < 32; k += 2) {
            const float2 av = *(const float2*)&as[bb][k];
            const float2 wv = *(const float2*)&ws[d][k];
            acc = fmaf(av.x, wv.x, acc); acc = fmaf(av.y, wv.y, acc);
        }
        __syncthreads();
    }
    const float v = acc + bias[d];
    s_buf[(b0 + bb) * DD + d] = v;
    s_out[(b0 + bb) * s_stride + d] = v;
}

extern "C" void kernel_launch(void* const* d_in, const int* in_sizes, int n_in,
                              void* d_out, int out_size, void* d_ws, size_t ws_size,
                              hipStream_t stream) {
    const float* state_seq = (const float*)d_in[0];  // [256,512,64]
    const float* W_ih  = (const float*)d_in[1];      // [1536,64]
    const float* W_hh  = (const float*)d_in[2];      // [1536,512]
    const float* b_ih  = (const float*)d_in[3];
    const float* b_hh  = (const float*)d_in[4];
    const float* fc1_w = (const float*)d_in[5];      // [512,512]
    const float* fc1_b = (const float*)d_in[6];
    const float* fc2_w = (const float*)d_in[7];      // [64,512]
    const float* fc2_b = (const float*)d_in[8];

    float* out_s = (float*)d_out;                    // [256, 32, 64]
    float* out_h = out_s + BB * FF * DD;             // [256, 32, 512]

    float* hA   = (float*)d_ws;
    float* hB   = hA + BB * HH;
    float* aBuf = hB + BB * HH;
    float* sBuf = aBuf + BB * HH;

    const dim3 blk(256);
    const dim3 gruGrid(HH / 4, BB / 64);             // (128, 4) = 512 wgs, 2/CU

    // ---- encoder: 512 per-step launches (launch boundary = h sync) ----
    const float* hcur = nullptr;
    for (int t = 0; t < TT; ++t) {
        float* hout = (t & 1) ? hB : hA;
        float* hout2 = (t == TT - 1) ? out_h : nullptr;   // h_seq[:,0,:]
        gru_step_wj<<<gruGrid, blk, 0, stream>>>(state_seq + t * DD, TT * DD, hcur,
                                                 W_ih, W_hh, b_ih, b_hh,
                                                 hout, hout2, FF * HH);
        hcur = hout;
    }

    // ---- decoder: 32 fc_predicts, 31 GRU steps ----
    for (int t = 0; t < FF; ++t) {
        fc1_relu<<<dim3(HH / 32, BB / 16), blk, 0, stream>>>(hcur, fc1_w, fc1_b, aBuf);
        fc2_out<<<dim3(BB / 4), blk, 0, stream>>>(aBuf, fc2_w, fc2_b, sBuf,
                                                  out_s + t * DD, FF * DD);
        if (t < FF - 1) {
            float* hout = (hcur == hA) ? hB : hA;
            gru_step_wj<<<gruGrid, blk, 0, stream>>>(sBuf, DD, hcur,
                                                     W_ih, W_hh, b_ih, b_hh,
                                                     hout, out_h + (t + 1) * HH, FF * HH);
            hcur = hout;
        }
    }
}